// Round 8
// baseline (341.149 us; speedup 1.0000x reference)
//
#include <hip/hip_runtime.h>

// Flash-attention fwd: B=4,H=16,S=2048,D=64, fp32 in/out.
// R9b: pair-rotated cross-phase pipeline, REGISTER-NEUTRAL vs R8.
// R9 post-mortem: 2nd bus set (+16 VGPR) blew the 128-VGPR launch_bounds
// cap -> scratch spill (WRITE_SIZE 32.8->315 MB, FETCH 33->200 MB,
// MfmaUtil 1-21%). Serialization theory unfalsified; implementation was.
// Fix: rotate schedule by one kb-pair using DISJOINT ENTRIES of the
// existing bus0/bus1[4]: each barrier-delimited region runs QK(pair j+1)
// (writes entries {2,3} or {0,1}) alongside PV(pair j) (reads the other
// pair, produced in the PREVIOUS region) -> MFMA->exp->MFMA chain cut by
// the fence, no extra state. One barrier/tile, mid-body. Everything else
// (V-direct-from-L2 fragment-ordered, K XOR-swizzle dbuf, prep) = R8.

#define S_LEN 2048
#define D_DIM 64
#define TK    64
#define NTILE (S_LEN / TK)          // 32
#define LOG2E_OVER8 0.18033688011112042f
#define VTILE (64 * 64)             // 4096 us per (bh,t) tile, fragment-ordered
#define VBH   (NTILE * VTILE)       // 131072 us per bh

typedef __bf16 bf16x8 __attribute__((ext_vector_type(8)));
typedef short  s16x4  __attribute__((ext_vector_type(4)));
typedef float  f32x4  __attribute__((ext_vector_type(4)));
typedef unsigned short us;

__device__ __forceinline__ us f2bf(float f) {
    union { __bf16 h; us u; } c;
    c.h = (__bf16)f;
    return c.u;
}

__device__ __forceinline__ unsigned pk2(float a, float b) {
#if __has_builtin(__builtin_amdgcn_cvt_pk_bf16_f32)
    typedef __bf16 bf2 __attribute__((ext_vector_type(2)));
    union { bf2 h; unsigned u; } c;
    c.h = __builtin_amdgcn_cvt_pk_bf16_f32(a, b);
    return c.u;
#else
    return ((unsigned)f2bf(b) << 16) | f2bf(a);
#endif
}

__device__ __forceinline__ float fast_exp2(float x) {
#if __has_builtin(__builtin_amdgcn_exp2f)
    return __builtin_amdgcn_exp2f(x);   // raw v_exp_f32; exact for |x| < 128
#else
    return exp2f(x);
#endif
}

__device__ __forceinline__ void gload_lds16(const void* g, void* l) {
    __builtin_amdgcn_global_load_lds(
        (const __attribute__((address_space(1))) unsigned int*)g,
        (__attribute__((address_space(3))) unsigned int*)l, 16, 0, 0);
}

__device__ __forceinline__ f32x4 mfma16x16x16(s16x4 a, s16x4 b, f32x4 c) {
#if __has_builtin(__builtin_amdgcn_mfma_f32_16x16x16bf16_1k)
    return __builtin_amdgcn_mfma_f32_16x16x16bf16_1k(a, b, c, 0, 0, 0);
#else
    f32x4 d = c;
    asm volatile("v_mfma_f32_16x16x16_bf16 %0, %1, %2, %0"
                 : "+v"(d) : "v"(a), "v"(b));
    return d;
#endif
}

// ---- pre-pass ---- (unchanged from R8)
// blocks [0,4096): K -> bf16 coalesced stream
// blocks [4096,6144): V [bh][s][d] fp32 -> fragment-ordered Vt: per (bh,t)
//   tile, 8 chunks (f = j*4 + db) x 64 lanes x 16B. Chunk f, lane l, us e:
//   V[t*64 + (2j+(e>>2))*16 + (l>>4)*4 + (e&3)][db*16 + (l&15)]  (bf16).
__global__ __launch_bounds__(256)
void prep(const float* __restrict__ K, const float* __restrict__ V,
          us* __restrict__ Kb, us* __restrict__ Vt) {
    __shared__ us Ls[64 * 68];
    const int bx = blockIdx.x, tid = threadIdx.x;
    if (bx < 4096) {
        const size_t i = ((size_t)bx * 256 + tid) * 8;
        const float4 a = *(const float4*)(K + i);
        const float4 b = *(const float4*)(K + i + 4);
        union { us u[8]; uint4 q; } pk;
        pk.u[0] = f2bf(a.x); pk.u[1] = f2bf(a.y);
        pk.u[2] = f2bf(a.z); pk.u[3] = f2bf(a.w);
        pk.u[4] = f2bf(b.x); pk.u[5] = f2bf(b.y);
        pk.u[6] = f2bf(b.z); pk.u[7] = f2bf(b.w);
        *(uint4*)(Kb + i) = pk.q;
    } else {
        const int idx = bx - 4096;
        const int t = idx & (NTILE - 1), bh = idx >> 5;
        {   // stage V[s=t*64..+64][d=0..64] as bf16 [64][68]
            const int r = tid >> 2, seg = tid & 3;
            const float* src = V + ((size_t)bh * S_LEN + t * TK + r) * D_DIM + seg * 16;
            us* dst = &Ls[r * 68 + seg * 16];
#pragma unroll
            for (int i = 0; i < 2; ++i) {
                const float4 v0 = *(const float4*)(src + 8 * i);
                const float4 v1 = *(const float4*)(src + 8 * i + 4);
                union { us u[8]; uint2 q[2]; } pk;
                pk.u[0] = f2bf(v0.x); pk.u[1] = f2bf(v0.y);
                pk.u[2] = f2bf(v0.z); pk.u[3] = f2bf(v0.w);
                pk.u[4] = f2bf(v1.x); pk.u[5] = f2bf(v1.y);
                pk.u[6] = f2bf(v1.z); pk.u[7] = f2bf(v1.w);
                *(uint2*)(dst + 8 * i) = pk.q[0];
                *(uint2*)(dst + 8 * i + 4) = pk.q[1];
            }
        }
        __syncthreads();
        {   // gather into MFMA-fragment-ordered 16B chunks
            const int lane = tid & 63, db = tid >> 6;
            const int quad = lane >> 4, l15 = lane & 15;
            const int d = db * 16 + l15;
            us* dst = Vt + (size_t)bh * VBH + t * VTILE + lane * 8;
#pragma unroll
            for (int c = 0; c < 2; ++c) {
                union { us u[8]; uint4 q; } pk;
#pragma unroll
                for (int e = 0; e < 8; ++e) {
                    const int k = (2 * c + (e >> 2)) * 16 + quad * 4 + (e & 3);
                    pk.u[e] = Ls[k * 68 + d];
                }
                *(uint4*)(dst + (c * 4 + db) * 512) = pk.q;
            }
        }
    }
}

// ---- main flash-attention kernel ----
// 1024 blocks; block = 128 queries (4 waves x 32 q); wave = 2 Q fragments.
__global__ __launch_bounds__(256, 4)
void fa_fwd(const float* __restrict__ Qg, const us* __restrict__ Kb,
            const us* __restrict__ Vtb, float* __restrict__ Og) {
    __shared__ __align__(16) us Kl[2][TK * 64];   // 2 x 8 KB K dbuf, XOR swizzle

    const int tid  = threadIdx.x;
    const int w    = tid >> 6;
    const int lane = tid & 63;
    const int l15  = lane & 15;
    const int quad = lane >> 4;
    const int x    = l15 & 7;

    // XCD-grouped swizzle: xcd = bid&7 owns bh in [xcd*8, +8); bijective.
    const int bid   = blockIdx.x;
    const int chunk = bid >> 3;
    const int bh    = ((bid & 7) << 3) | (chunk >> 4);
    const int qb    = chunk & 15;
    const size_t base = (size_t)bh * S_LEN * D_DIM;

    // ---- 2 Q fragments from fp32, scale folded (B operand of S^T) ----
    bf16x8 bq00, bq01, bq10, bq11;   // [qh][k-half]
    {
        const float* q0 = Qg + base + (size_t)(qb * 128 + w * 32 + l15) * D_DIM + quad * 8;
        const float* q1 = q0 + 16 * D_DIM;
#define LOADQ(dst0, dst1, p)                                                  \
        {                                                                     \
            const float4 x0 = *(const float4*)(p);                            \
            const float4 x1 = *(const float4*)((p) + 4);                      \
            const float4 y0 = *(const float4*)((p) + 32);                     \
            const float4 y1 = *(const float4*)((p) + 36);                     \
            dst0[0]=(__bf16)(x0.x*LOG2E_OVER8); dst0[1]=(__bf16)(x0.y*LOG2E_OVER8); \
            dst0[2]=(__bf16)(x0.z*LOG2E_OVER8); dst0[3]=(__bf16)(x0.w*LOG2E_OVER8); \
            dst0[4]=(__bf16)(x1.x*LOG2E_OVER8); dst0[5]=(__bf16)(x1.y*LOG2E_OVER8); \
            dst0[6]=(__bf16)(x1.z*LOG2E_OVER8); dst0[7]=(__bf16)(x1.w*LOG2E_OVER8); \
            dst1[0]=(__bf16)(y0.x*LOG2E_OVER8); dst1[1]=(__bf16)(y0.y*LOG2E_OVER8); \
            dst1[2]=(__bf16)(y0.z*LOG2E_OVER8); dst1[3]=(__bf16)(y0.w*LOG2E_OVER8); \
            dst1[4]=(__bf16)(y1.x*LOG2E_OVER8); dst1[5]=(__bf16)(y1.y*LOG2E_OVER8); \
            dst1[6]=(__bf16)(y1.z*LOG2E_OVER8); dst1[7]=(__bf16)(y1.w*LOG2E_OVER8); \
        }
        LOADQ(bq00, bq01, q0)
        LOADQ(bq10, bq11, q1)
#undef LOADQ
    }

    // ---- staging addresses ----
    const int krow   = w * 16 + (lane >> 3);
    const int kchunk = (lane & 7) ^ (lane >> 3);
    const us* ksrc = Kb + base + (size_t)krow * D_DIM + kchunk * 8;
    const us* vg0 = Vtb + (size_t)bh * VBH + lane * 8;

    float lv0 = 0.f, lv1 = 0.f;
    f32x4 oa0[4], oa1[4];
#pragma unroll
    for (int db = 0; db < 4; ++db) {
        oa0[db] = (f32x4){0.f, 0.f, 0.f, 0.f};
        oa1[db] = (f32x4){0.f, 0.f, 0.f, 0.f};
    }

    // ONE bus set (same as R8): entries {0,1} and {2,3} rotate roles.
    s16x4 bus0[4], bus1[4];
    uint4 vqa[4];

#define QK_STEP(KL, kb)                                                        \
    {                                                                          \
        const int row_ = (kb) * 16 + l15;                                      \
        const bf16x8 a0 = *(const bf16x8*)&(KL)[row_ * 64 + ((quad ^ x) * 8)]; \
        const bf16x8 a1 = *(const bf16x8*)&(KL)[row_ * 64 + (((4 + quad) ^ x) * 8)]; \
        f32x4 c0 = {0.f, 0.f, 0.f, 0.f};                                       \
        c0 = __builtin_amdgcn_mfma_f32_16x16x32_bf16(a0, bq00, c0, 0, 0, 0);   \
        c0 = __builtin_amdgcn_mfma_f32_16x16x32_bf16(a1, bq01, c0, 0, 0, 0);   \
        f32x4 c1 = {0.f, 0.f, 0.f, 0.f};                                       \
        c1 = __builtin_amdgcn_mfma_f32_16x16x32_bf16(a0, bq10, c1, 0, 0, 0);   \
        c1 = __builtin_amdgcn_mfma_f32_16x16x32_bf16(a1, bq11, c1, 0, 0, 0);   \
        const float p00 = fast_exp2(c0[0]), p01 = fast_exp2(c0[1]);            \
        const float p02 = fast_exp2(c0[2]), p03 = fast_exp2(c0[3]);            \
        lv0 += (p00 + p01) + (p02 + p03);                                      \
        const float p10 = fast_exp2(c1[0]), p11 = fast_exp2(c1[1]);            \
        const float p12 = fast_exp2(c1[2]), p13 = fast_exp2(c1[3]);            \
        lv1 += (p10 + p11) + (p12 + p13);                                      \
        union { unsigned u[2]; s16x4 s; } b0_, b1_;                            \
        b0_.u[0] = pk2(p00, p01); b0_.u[1] = pk2(p02, p03);                    \
        b1_.u[0] = pk2(p10, p11); b1_.u[1] = pk2(p12, p13);                    \
        bus0[kb] = b0_.s; bus1[kb] = b1_.s;                                    \
    }

#define PV_PAIR(K0)                                                            \
    _Pragma("unroll")                                                          \
    for (int db = 0; db < 4; ++db) {                                           \
        union { uint4 q; s16x4 s[2]; } va;                                     \
        va.q = vqa[db];                                                        \
        oa0[db] = mfma16x16x16(va.s[0], bus0[K0], oa0[db]);                    \
        oa1[db] = mfma16x16x16(va.s[0], bus1[K0], oa1[db]);                    \
        oa0[db] = mfma16x16x16(va.s[1], bus0[(K0) + 1], oa0[db]);              \
        oa1[db] = mfma16x16x16(va.s[1], bus1[(K0) + 1], oa1[db]);              \
    }

#define VLOAD(T, F0)                                                           \
    _Pragma("unroll")                                                          \
    for (int f = 0; f < 4; ++f)                                                \
        vqa[f] = *(const uint4*)(vg0 + (size_t)(T) * VTILE + ((F0) + f) * 512);

    // Body for tile T. Region 1 (pre-barrier): QK(T,2/3) writes bus{2,3}
    // while PV(T,pair0) reads bus{0,1} (produced in the previous region).
    // Region 2 (post-barrier): QK(T+1,0/1) writes bus{0,1} while PV(T,pair1)
    // reads bus{2,3}. Barrier also covers: Kl[T&1]'s last reader (QK(T,2/3))
    // before the K(T+2) prefetch overwrites it, and K(T+1)'s gload (issued
    // in body T-1) landing before QK(T+1) reads Kl[(T+1)&1].
#define TILE_BODY(T, KLT, KLT1, DOPF)                                          \
    {                                                                          \
        QK_STEP(KLT, 2)                                                        \
        QK_STEP(KLT, 3)                                                        \
        PV_PAIR(0)                                                             \
        VLOAD(T, 4)                                                            \
        __syncthreads();                                                       \
        if (DOPF) {                                                            \
            const us* ks_ = ksrc + (size_t)((T) + 2) * (TK * D_DIM);           \
            us* kd_ = &(KLT)[w * 1024];                                        \
            gload_lds16(ks_, kd_);                                             \
            gload_lds16(ks_ + 512, kd_ + 512);                                 \
        }                                                                      \
        QK_STEP(KLT1, 0)                                                       \
        QK_STEP(KLT1, 1)                                                       \
        PV_PAIR(2)                                                             \
        VLOAD((T) + 1, 0)                                                      \
    }

    // ---- prologue: stage K0; prefetch K1; QK(0,0/1) -> bus{0,1}; V(0,f0-3)
    gload_lds16(ksrc, &Kl[0][w * 1024]);
    gload_lds16(ksrc + 512, &Kl[0][w * 1024 + 512]);
    __syncthreads();
    {
        const us* ks_ = ksrc + (size_t)(TK * D_DIM);
        us* kd_ = &Kl[1][w * 1024];
        gload_lds16(ks_, kd_);
        gload_lds16(ks_ + 512, kd_ + 512);
    }
    QK_STEP(Kl[0], 0)
    QK_STEP(Kl[0], 1)
    VLOAD(0, 0)

    // ---- main loop: tiles 0..29 (2x unrolled for Kl parity), then 30 ----
#pragma unroll 1
    for (int it = 0; it < 15; ++it) {
        TILE_BODY(2 * it,     Kl[0], Kl[1], 1)
        TILE_BODY(2 * it + 1, Kl[1], Kl[0], 1)
    }
    TILE_BODY(30, Kl[0], Kl[1], 0)

    // ---- tail: tile 31 (bus{0,1}=QK(31,0/1), vqa=V(31,f0-3) from body 30)
    QK_STEP(Kl[1], 2)
    QK_STEP(Kl[1], 3)
    PV_PAIR(0)
    VLOAD(31, 4)
    PV_PAIR(2)

#undef QK_STEP
#undef PV_PAIR
#undef VLOAD
#undef TILE_BODY

    // ---- normalization epilogue: two query rows per lane ----
    float lq0 = lv0;
    lq0 += __shfl_xor(lq0, 16, 64);
    lq0 += __shfl_xor(lq0, 32, 64);
    float lq1 = lv1;
    lq1 += __shfl_xor(lq1, 16, 64);
    lq1 += __shfl_xor(lq1, 32, 64);
    const float inv0 = 1.f / lq0;
    const float inv1 = 1.f / lq1;
    float* op0 = Og + base + (size_t)(qb * 128 + w * 32 + l15) * D_DIM + quad * 4;
    float* op1 = op0 + 16 * D_DIM;
#pragma unroll
    for (int db = 0; db < 4; ++db) {
        float4 v0 = { oa0[db][0] * inv0, oa0[db][1] * inv0,
                      oa0[db][2] * inv0, oa0[db][3] * inv0 };
        *(float4*)(op0 + db * 16) = v0;
        float4 v1 = { oa1[db][0] * inv1, oa1[db][1] * inv1,
                      oa1[db][2] * inv1, oa1[db][3] * inv1 };
        *(float4*)(op1 + db * 16) = v1;
    }
}

extern "C" void kernel_launch(void* const* d_in, const int* in_sizes, int n_in,
                              void* d_out, int out_size, void* d_ws, size_t ws_size,
                              hipStream_t stream) {
    const float* Q = (const float*)d_in[0];
    const float* K = (const float*)d_in[1];
    const float* V = (const float*)d_in[2];
    float* O = (float*)d_out;

    us* Kb = (us*)d_ws;                                  // 16.78 MB
    us* Vt = Kb + (size_t)64 * S_LEN * D_DIM;            // 16.78 MB

    prep<<<4096 + 2048, 256, 0, stream>>>(K, V, Kb, Vt);
    fa_fwd<<<dim3(1024), 256, 0, stream>>>(Q, Kb, Vt, O);
}

// Round 9
// 214.854 us; speedup vs baseline: 1.5878x; 1.5878x over previous
//
#include <hip/hip_runtime.h>

// Flash-attention fwd: B=4,H=16,S=2048,D=64, fp32 in/out.
// R10: ZERO-LDS, ZERO-BARRIER fa_fwd. R9/R9b both died to scratch spill
// (WRITE_SIZE 315/440 MB) — source-level pipelining stretches live ranges
// past the VGPR cap (guide m131-141). Different attack: R8's counters
// proved K/V fully L2-resident (FETCH == unique inputs), so K joins V in
// fragment-ordered global layout (prep gather replaces the Kb stream) and
// fa_fwd reads BOTH operands straight from L2 into VGPRs. No __shared__,
// no __syncthreads, no gload_lds: 16 independent free-running waves/CU do
// the overlap (m114) that manual scheduling couldn't. K/V quads die within
// their half-tile -> peak VMEM-live 32 VGPR. launch_bounds(256,3) relaxes
// the cap to ~170: failure mode is mild occupancy loss, not the 2x spill
// cliff. Math/fragments identical to harness-verified R8 (absmax 0.00195).

#define S_LEN 2048
#define D_DIM 64
#define TK    64
#define NTILE (S_LEN / TK)          // 32
#define LOG2E_OVER8 0.18033688011112042f
#define VTILE (64 * 64)             // 4096 us per (bh,t) tile, fragment-ordered
#define VBH   (NTILE * VTILE)       // 131072 us per bh (K and V alike)

typedef __bf16 bf16x8 __attribute__((ext_vector_type(8)));
typedef short  s16x4  __attribute__((ext_vector_type(4)));
typedef float  f32x4  __attribute__((ext_vector_type(4)));
typedef unsigned short us;

__device__ __forceinline__ us f2bf(float f) {
    union { __bf16 h; us u; } c;
    c.h = (__bf16)f;
    return c.u;
}

__device__ __forceinline__ unsigned pk2(float a, float b) {
#if __has_builtin(__builtin_amdgcn_cvt_pk_bf16_f32)
    typedef __bf16 bf2 __attribute__((ext_vector_type(2)));
    union { bf2 h; unsigned u; } c;
    c.h = __builtin_amdgcn_cvt_pk_bf16_f32(a, b);
    return c.u;
#else
    return ((unsigned)f2bf(b) << 16) | f2bf(a);
#endif
}

__device__ __forceinline__ float fast_exp2(float x) {
#if __has_builtin(__builtin_amdgcn_exp2f)
    return __builtin_amdgcn_exp2f(x);   // raw v_exp_f32; exact for |x| < 128
#else
    return exp2f(x);
#endif
}

__device__ __forceinline__ f32x4 mfma16x16x16(s16x4 a, s16x4 b, f32x4 c) {
#if __has_builtin(__builtin_amdgcn_mfma_f32_16x16x16bf16_1k)
    return __builtin_amdgcn_mfma_f32_16x16x16bf16_1k(a, b, c, 0, 0, 0);
#else
    f32x4 d = c;
    asm volatile("v_mfma_f32_16x16x16_bf16 %0, %1, %2, %0"
                 : "+v"(d) : "v"(a), "v"(b));
    return d;
#endif
}

// ---- pre-pass (grid 4096) ----
// blocks [0,2048):    V tiles -> fragment-ordered Vt (unchanged from R8):
//   chunk f=c*4+db, lane l, us e: V[t*64+(2c+(e>>2))*16+(l>>4)*4+(e&3)][db*16+(l&15)]
// blocks [2048,4096): K tiles -> fragment-ordered Kt:
//   chunk f=kb*2+half, lane l, us e: K[t*64+(f>>1)*16+(l&15)][((f&1)*4+(l>>4))*8+e]
//   (exactly the QK A-operand fragments the R8 kernel read from LDS)
__global__ __launch_bounds__(256)
void prep(const float* __restrict__ K, const float* __restrict__ V,
          us* __restrict__ Kt, us* __restrict__ Vt) {
    __shared__ us Ls[64 * 68];
    const int bx = blockIdx.x, tid = threadIdx.x;
    const bool isV = bx < 2048;
    const int idx = isV ? bx : bx - 2048;
    const int t = idx & (NTILE - 1), bh = idx >> 5;
    {   // stage src[s=t*64..+64][d=0..64] as bf16 [64][68]
        const float* sb = isV ? V : K;
        const int r = tid >> 2, seg = tid & 3;
        const float* src = sb + ((size_t)bh * S_LEN + t * TK + r) * D_DIM + seg * 16;
        us* dst = &Ls[r * 68 + seg * 16];
#pragma unroll
        for (int i = 0; i < 2; ++i) {
            const float4 v0 = *(const float4*)(src + 8 * i);
            const float4 v1 = *(const float4*)(src + 8 * i + 4);
            union { us u[8]; uint2 q[2]; } pk;
            pk.u[0] = f2bf(v0.x); pk.u[1] = f2bf(v0.y);
            pk.u[2] = f2bf(v0.z); pk.u[3] = f2bf(v0.w);
            pk.u[4] = f2bf(v1.x); pk.u[5] = f2bf(v1.y);
            pk.u[6] = f2bf(v1.z); pk.u[7] = f2bf(v1.w);
            *(uint2*)(dst + 8 * i) = pk.q[0];
            *(uint2*)(dst + 8 * i + 4) = pk.q[1];
        }
    }
    __syncthreads();
    if (isV) {   // gather V^T fragments (R8 code)
        const int lane = tid & 63, db = tid >> 6;
        const int quad = lane >> 4, l15 = lane & 15;
        const int d = db * 16 + l15;
        us* dst = Vt + (size_t)bh * VBH + t * VTILE + lane * 8;
#pragma unroll
        for (int c = 0; c < 2; ++c) {
            union { us u[8]; uint4 q; } pk;
#pragma unroll
            for (int e = 0; e < 8; ++e) {
                const int k = (2 * c + (e >> 2)) * 16 + quad * 4 + (e & 3);
                pk.u[e] = Ls[k * 68 + d];
            }
            *(uint4*)(dst + (c * 4 + db) * 512) = pk.q;
        }
    } else {     // gather K row fragments: thread -> chunks 2*fhi, 2*fhi+1
        const int lane = tid & 63, fhi = tid >> 6;
        const int quad = lane >> 4, l15 = lane & 15;
        const int row = fhi * 16 + l15;
        us* dst = Kt + (size_t)bh * VBH + t * VTILE + lane * 8;
        union { us u[8]; uint4 q; } p0, p1;
#pragma unroll
        for (int e = 0; e < 8; ++e) {
            p0.u[e] = Ls[row * 68 + quad * 8 + e];
            p1.u[e] = Ls[row * 68 + (quad + 4) * 8 + e];
        }
        *(uint4*)(dst + (2 * fhi) * 512) = p0.q;
        *(uint4*)(dst + (2 * fhi + 1) * 512) = p1.q;
    }
}

// ---- main flash-attention kernel ----
// 1024 blocks x 4 waves; wave = 32 queries (2 Q frags); NO LDS, NO BARRIERS.
__global__ __launch_bounds__(256, 3)
void fa_fwd(const float* __restrict__ Qg, const us* __restrict__ Ktb,
            const us* __restrict__ Vtb, float* __restrict__ Og) {
    const int tid  = threadIdx.x;
    const int w    = tid >> 6;
    const int lane = tid & 63;
    const int l15  = lane & 15;
    const int quad = lane >> 4;

    // XCD-grouped swizzle: xcd = bid&7 owns bh in [xcd*8, +8); bijective.
    const int bid   = blockIdx.x;
    const int chunk = bid >> 3;
    const int bh    = ((bid & 7) << 3) | (chunk >> 4);
    const int qb    = chunk & 15;
    const size_t base = (size_t)bh * S_LEN * D_DIM;

    // ---- 2 Q fragments from fp32, scale folded (B operand of S^T) ----
    bf16x8 bq00, bq01, bq10, bq11;   // [qh][k-half]
    {
        const float* q0 = Qg + base + (size_t)(qb * 128 + w * 32 + l15) * D_DIM + quad * 8;
        const float* q1 = q0 + 16 * D_DIM;
#define LOADQ(dst0, dst1, p)                                                  \
        {                                                                     \
            const float4 x0 = *(const float4*)(p);                            \
            const float4 x1 = *(const float4*)((p) + 4);                      \
            const float4 y0 = *(const float4*)((p) + 32);                     \
            const float4 y1 = *(const float4*)((p) + 36);                     \
            dst0[0]=(__bf16)(x0.x*LOG2E_OVER8); dst0[1]=(__bf16)(x0.y*LOG2E_OVER8); \
            dst0[2]=(__bf16)(x0.z*LOG2E_OVER8); dst0[3]=(__bf16)(x0.w*LOG2E_OVER8); \
            dst0[4]=(__bf16)(x1.x*LOG2E_OVER8); dst0[5]=(__bf16)(x1.y*LOG2E_OVER8); \
            dst0[6]=(__bf16)(x1.z*LOG2E_OVER8); dst0[7]=(__bf16)(x1.w*LOG2E_OVER8); \
            dst1[0]=(__bf16)(y0.x*LOG2E_OVER8); dst1[1]=(__bf16)(y0.y*LOG2E_OVER8); \
            dst1[2]=(__bf16)(y0.z*LOG2E_OVER8); dst1[3]=(__bf16)(y0.w*LOG2E_OVER8); \
            dst1[4]=(__bf16)(y1.x*LOG2E_OVER8); dst1[5]=(__bf16)(y1.y*LOG2E_OVER8); \
            dst1[6]=(__bf16)(y1.z*LOG2E_OVER8); dst1[7]=(__bf16)(y1.w*LOG2E_OVER8); \
        }
        LOADQ(bq00, bq01, q0)
        LOADQ(bq10, bq11, q1)
#undef LOADQ
    }

    // ---- per-lane K/V fragment bases (fragment-ordered global tiles) ----
    const us* kg0 = Ktb + (size_t)bh * VBH + lane * 8;
    const us* vg0 = Vtb + (size_t)bh * VBH + lane * 8;

    float lv0 = 0.f, lv1 = 0.f;
    f32x4 oa0[4], oa1[4];
#pragma unroll
    for (int db = 0; db < 4; ++db) {
        oa0[db] = (f32x4){0.f, 0.f, 0.f, 0.f};
        oa1[db] = (f32x4){0.f, 0.f, 0.f, 0.f};
    }

    s16x4 bus0[4], bus1[4];

#define QK_STEP(kb, KA, KB)                                                    \
    {                                                                          \
        union { uint4 q; bf16x8 h; } aU, bU;                                   \
        aU.q = (KA); bU.q = (KB);                                              \
        f32x4 c0 = {0.f, 0.f, 0.f, 0.f};                                       \
        c0 = __builtin_amdgcn_mfma_f32_16x16x32_bf16(aU.h, bq00, c0, 0, 0, 0); \
        c0 = __builtin_amdgcn_mfma_f32_16x16x32_bf16(bU.h, bq01, c0, 0, 0, 0); \
        f32x4 c1 = {0.f, 0.f, 0.f, 0.f};                                       \
        c1 = __builtin_amdgcn_mfma_f32_16x16x32_bf16(aU.h, bq10, c1, 0, 0, 0); \
        c1 = __builtin_amdgcn_mfma_f32_16x16x32_bf16(bU.h, bq11, c1, 0, 0, 0); \
        const float p00 = fast_exp2(c0[0]), p01 = fast_exp2(c0[1]);            \
        const float p02 = fast_exp2(c0[2]), p03 = fast_exp2(c0[3]);            \
        lv0 += (p00 + p01) + (p02 + p03);                                      \
        const float p10 = fast_exp2(c1[0]), p11 = fast_exp2(c1[1]);            \
        const float p12 = fast_exp2(c1[2]), p13 = fast_exp2(c1[3]);            \
        lv1 += (p10 + p11) + (p12 + p13);                                      \
        union { unsigned u[2]; s16x4 s; } b0_, b1_;                            \
        b0_.u[0] = pk2(p00, p01); b0_.u[1] = pk2(p02, p03);                    \
        b1_.u[0] = pk2(p10, p11); b1_.u[1] = pk2(p12, p13);                    \
        bus0[kb] = b0_.s; bus1[kb] = b1_.s;                                    \
    }

#define PV_ONE(VQ, DB, K0)                                                     \
    {                                                                          \
        union { uint4 q; s16x4 s[2]; } va;                                     \
        va.q = (VQ);                                                           \
        oa0[DB] = mfma16x16x16(va.s[0], bus0[K0], oa0[DB]);                    \
        oa1[DB] = mfma16x16x16(va.s[0], bus1[K0], oa1[DB]);                    \
        oa0[DB] = mfma16x16x16(va.s[1], bus0[(K0) + 1], oa0[DB]);              \
        oa1[DB] = mfma16x16x16(va.s[1], bus1[(K0) + 1], oa1[DB]);              \
    }

#pragma unroll 1
    for (int t = 0; t < NTILE; ++t) {
        const us* kg = kg0 + (size_t)t * VTILE;
        const us* vg = vg0 + (size_t)t * VTILE;

        // half-tile 0: K chunks 0-3 (kb0/1) + V chunks 0-3
        const uint4 k0 = *(const uint4*)(kg);
        const uint4 k1 = *(const uint4*)(kg + 512);
        const uint4 k2 = *(const uint4*)(kg + 1024);
        const uint4 k3 = *(const uint4*)(kg + 1536);
        const uint4 v0 = *(const uint4*)(vg);
        const uint4 v1 = *(const uint4*)(vg + 512);
        const uint4 v2 = *(const uint4*)(vg + 1024);
        const uint4 v3 = *(const uint4*)(vg + 1536);
        QK_STEP(0, k0, k1)
        QK_STEP(1, k2, k3)
        // half-tile 1 loads issued here; latency hides under PV(pair0)
        const uint4 k4 = *(const uint4*)(kg + 2048);
        const uint4 k5 = *(const uint4*)(kg + 2560);
        const uint4 k6 = *(const uint4*)(kg + 3072);
        const uint4 k7 = *(const uint4*)(kg + 3584);
        PV_ONE(v0, 0, 0) PV_ONE(v1, 1, 0) PV_ONE(v2, 2, 0) PV_ONE(v3, 3, 0)
        const uint4 v4 = *(const uint4*)(vg + 2048);
        const uint4 v5 = *(const uint4*)(vg + 2560);
        const uint4 v6 = *(const uint4*)(vg + 3072);
        const uint4 v7 = *(const uint4*)(vg + 3584);
        QK_STEP(2, k4, k5)
        QK_STEP(3, k6, k7)
        PV_ONE(v4, 0, 2) PV_ONE(v5, 1, 2) PV_ONE(v6, 2, 2) PV_ONE(v7, 3, 2)
    }
#undef QK_STEP
#undef PV_ONE

    // ---- normalization epilogue: two query rows per lane ----
    float lq0 = lv0;
    lq0 += __shfl_xor(lq0, 16, 64);
    lq0 += __shfl_xor(lq0, 32, 64);
    float lq1 = lv1;
    lq1 += __shfl_xor(lq1, 16, 64);
    lq1 += __shfl_xor(lq1, 32, 64);
    const float inv0 = 1.f / lq0;
    const float inv1 = 1.f / lq1;
    float* op0 = Og + base + (size_t)(qb * 128 + w * 32 + l15) * D_DIM + quad * 4;
    float* op1 = op0 + 16 * D_DIM;
#pragma unroll
    for (int db = 0; db < 4; ++db) {
        float4 v0 = { oa0[db][0] * inv0, oa0[db][1] * inv0,
                      oa0[db][2] * inv0, oa0[db][3] * inv0 };
        *(float4*)(op0 + db * 16) = v0;
        float4 v1 = { oa1[db][0] * inv1, oa1[db][1] * inv1,
                      oa1[db][2] * inv1, oa1[db][3] * inv1 };
        *(float4*)(op1 + db * 16) = v1;
    }
}

extern "C" void kernel_launch(void* const* d_in, const int* in_sizes, int n_in,
                              void* d_out, int out_size, void* d_ws, size_t ws_size,
                              hipStream_t stream) {
    const float* Q = (const float*)d_in[0];
    const float* K = (const float*)d_in[1];
    const float* V = (const float*)d_in[2];
    float* O = (float*)d_out;

    us* Kt = (us*)d_ws;                                  // 16.78 MB
    us* Vt = Kt + (size_t)64 * VBH;                      // 16.78 MB

    prep<<<4096, 256, 0, stream>>>(K, V, Kt, Vt);
    fa_fwd<<<dim3(1024), 256, 0, stream>>>(Q, Kt, Vt, O);
}